// Round 1
// baseline (32.375 us; speedup 1.0000x reference)
//
#include <hip/hip_runtime.h>

#define NIN 8
#define NMF 4
#define NRULES 65536
#define NBATCH 1024
#define TB 8          // batches per block in main kernel
#define RSPLITS 8     // rule splits (over hi)
#define NHI 256       // 4^4
#define HPB (NHI / RSPLITS)  // hi values per block = 32

// ws layout (floats):
//   memb : [0, 32768)          m[b][i][q] at b*32 + i*4 + q
//   den  : [32768, 33792)      den[b]
//   part : [33792, 41984)      part[rsplit][b] at 33792 + rsplit*1024 + b
#define WS_MEMB 0
#define WS_DEN  32768
#define WS_PART 33792

__global__ __launch_bounds__(64) void anfis_memb(
    const float* __restrict__ x, const float* __restrict__ mu,
    const float* __restrict__ sigma, float* __restrict__ memb,
    float* __restrict__ den) {
    int b = blockIdx.x;
    int t = threadIdx.x;
    __shared__ float ms[32];
    if (t < 32) {
        int i = t >> 2, q = t & 3;
        float s = fabsf(sigma[i * 4 + q]) + 1e-5f;
        float inv2v = 1.0f / (2.0f * s * s);
        float d = x[b * 8 + i] - mu[i * 4 + q];
        float m = expf(-d * d * inv2v);
        ms[t] = m;
        memb[b * 32 + t] = m;
    }
    __syncthreads();
    if (t == 0) {
        // sum over all rules of prod(memb) = prod over inputs of row-sums
        float dn = 1.0f;
#pragma unroll
        for (int i = 0; i < 8; ++i)
            dn *= (ms[i * 4 + 0] + ms[i * 4 + 1] + ms[i * 4 + 2] + ms[i * 4 + 3]);
        den[b] = dn;
    }
}

__global__ __launch_bounds__(256) void anfis_main(
    const float* __restrict__ x, const float* __restrict__ cw,
    const float* __restrict__ cb, const float* __restrict__ memb,
    float* __restrict__ part) {
    int bid = blockIdx.x;
    int btile = bid >> 3;   // 0..127
    int rsplit = bid & 7;   // 0..7
    int b0 = btile * TB;
    int hi0 = rsplit * HPB;
    int t = threadIdx.x;    // lo lane = t (0..255)

    __shared__ float ms[TB][32];
    __shared__ float whi_s[HPB][TB];
    __shared__ float red[4][TB];

    // stage membership tile
    {
        int bb = t >> 5, j = t & 31;
        ms[bb][j] = memb[(b0 + bb) * 32 + j];
    }
    __syncthreads();

    // whi for this block's hi-range (hi digits are inputs 0..3)
    {
        int h = t >> 3, bb = t & 7;
        int hi = hi0 + h;
        int d0 = (hi >> 6) & 3, d1 = (hi >> 4) & 3, d2 = (hi >> 2) & 3, d3 = hi & 3;
        whi_s[h][bb] = ms[bb][0 + d0] * ms[bb][4 + d1] * ms[bb][8 + d2] * ms[bb][12 + d3];
    }

    // wlo per thread (lo digits are inputs 4..7)
    float wlo[TB];
    {
        int e0 = (t >> 6) & 3, e1 = (t >> 4) & 3, e2 = (t >> 2) & 3, e3 = t & 3;
#pragma unroll
        for (int bb = 0; bb < TB; ++bb)
            wlo[bb] = ms[bb][16 + e0] * ms[bb][20 + e1] * ms[bb][24 + e2] * ms[bb][28 + e3];
    }

    // x tile: wave-uniform addresses -> scalar loads/regs
    float xs[TB][8];
#pragma unroll
    for (int bb = 0; bb < TB; ++bb)
#pragma unroll
        for (int k = 0; k < 8; ++k)
            xs[bb][k] = x[(b0 + bb) * 8 + k];

    __syncthreads();

    float num[TB];
#pragma unroll
    for (int bb = 0; bb < TB; ++bb) num[bb] = 0.0f;

    for (int h = 0; h < HPB; ++h) {
        int r = (hi0 + h) * 256 + t;
        const float4* cwp = (const float4*)(cw + (size_t)r * 8);
        float4 c0 = cwp[0];
        float4 c1 = cwp[1];
        float cbv = cb[r];
#pragma unroll
        for (int bb = 0; bb < TB; ++bb) {
            float w = whi_s[h][bb] * wlo[bb];
            float dot = cbv;
            dot = fmaf(xs[bb][0], c0.x, dot);
            dot = fmaf(xs[bb][1], c0.y, dot);
            dot = fmaf(xs[bb][2], c0.z, dot);
            dot = fmaf(xs[bb][3], c0.w, dot);
            dot = fmaf(xs[bb][4], c1.x, dot);
            dot = fmaf(xs[bb][5], c1.y, dot);
            dot = fmaf(xs[bb][6], c1.z, dot);
            dot = fmaf(xs[bb][7], c1.w, dot);
            num[bb] = fmaf(w, dot, num[bb]);
        }
    }

    // reduce num across the 256 threads (sum over lo within this rsplit)
    int lane = t & 63, wv = t >> 6;
#pragma unroll
    for (int bb = 0; bb < TB; ++bb) {
        float v = num[bb];
#pragma unroll
        for (int off = 32; off > 0; off >>= 1) v += __shfl_xor(v, off);
        if (lane == 0) red[wv][bb] = v;
    }
    __syncthreads();
    if (t < TB) {
        float v = red[0][t] + red[1][t] + red[2][t] + red[3][t];
        part[rsplit * NBATCH + b0 + t] = v;
    }
}

__global__ __launch_bounds__(256) void anfis_final(
    const float* __restrict__ part, const float* __restrict__ den,
    float* __restrict__ out) {
    int b = blockIdx.x * 256 + threadIdx.x;
    if (b < NBATCH) {
        float num = 0.0f;
#pragma unroll
        for (int s = 0; s < RSPLITS; ++s) num += part[s * NBATCH + b];
        out[b] = num / (den[b] + 1e-6f);
    }
}

extern "C" void kernel_launch(void* const* d_in, const int* in_sizes, int n_in,
                              void* d_out, int out_size, void* d_ws, size_t ws_size,
                              hipStream_t stream) {
    const float* x     = (const float*)d_in[0];
    const float* mu    = (const float*)d_in[1];
    const float* sigma = (const float*)d_in[2];
    const float* cw    = (const float*)d_in[3];
    const float* cb    = (const float*)d_in[4];
    float* ws = (float*)d_ws;
    float* memb = ws + WS_MEMB;
    float* den  = ws + WS_DEN;
    float* part = ws + WS_PART;
    float* out  = (float*)d_out;

    anfis_memb<<<NBATCH, 64, 0, stream>>>(x, mu, sigma, memb, den);
    anfis_main<<<(NBATCH / TB) * RSPLITS, 256, 0, stream>>>(x, cw, cb, memb, part);
    anfis_final<<<NBATCH / 256, 256, 0, stream>>>(part, den, out);
}